// Round 1
// baseline (203.898 us; speedup 1.0000x reference)
//
#include <hip/hip_runtime.h>
#include <hip/hip_cooperative_groups.h>

namespace cg = cooperative_groups;

#define NB 32
#define NN 256
#define DD 64
#define GG 4            // node-groups per batch
#define NPB 64          // nodes per block

// R7: single cooperative kernel. R6's 4 dispatches + harness re-poison fills
// dominated the timed window (all top-5 rocprof dispatches were 256MiB
// fillBufferAligned @40us; our kernels sum to ~10us of real work). Fuse all
// stages with grid.sync(); identical (b,n,d0)->thread mapping lets ti live in
// REGISTERS across stages, deleting the 2MB TI buffer and its global
// round-trips. ws now holds only the cross-block tj/pool partials:
//   PMAX1 @0      NB*GG*DD = 8192 floats
//   PMIN1 @8192
//   PMAX2 @16384
//   PMIN2 @24576
//   PSUM  @32768
//   PMXP  @40960   (total 49152 floats = 192 KB)
// Partials are read back through the non-restrict ws pointer (vector loads,
// honors grid.sync's agent-scope acquire across XCD L2s).

__device__ __forceinline__ void matvec64(const float* Hrow, int d0,
                                         const float* __restrict__ We,
                                         float ti[8], float tj[8])
{
#pragma unroll
    for (int j = 0; j < 8; ++j) { ti[j] = 0.f; tj[j] = 0.f; }
#pragma unroll
    for (int k = 0; k < DD; ++k) {
        const float hk = Hrow[k];
        const float* wi = We + k * DD + d0;          // wave-uniform -> s_load
        const float* wj = We + (DD + k) * DD + d0;   // wave-uniform -> s_load
#pragma unroll
        for (int j = 0; j < 8; ++j) {
            ti[j] = fmaf(hk, wi[j], ti[j]);
            tj[j] = fmaf(hk, wj[j], tj[j]);
        }
    }
}

// butterfly max/min of tj over the 64 lanes; lanes 0..7 store dims d0+0..7
__device__ __forceinline__ void red_minmax_store(const float tj[8], int l,
                                                 float* PMAX, float* PMIN, int idx)
{
    float mx[8], mn[8];
#pragma unroll
    for (int j = 0; j < 8; ++j) { mx[j] = tj[j]; mn[j] = tj[j]; }
#pragma unroll
    for (int m = 1; m < 64; m <<= 1) {
#pragma unroll
        for (int j = 0; j < 8; ++j) {
            mx[j] = fmaxf(mx[j], __shfl_xor(mx[j], m, 64));
            mn[j] = fminf(mn[j], __shfl_xor(mn[j], m, 64));
        }
    }
    float smx = mx[0], smn = mn[0];
#pragma unroll
    for (int j = 1; j < 8; ++j) {
        smx = (l == j) ? mx[j] : smx;
        smn = (l == j) ? mn[j] : smn;
    }
    if (l < 8) {
        PMAX[idx + l] = smx;
        PMIN[idx + l] = smn;
    }
}

__global__ __launch_bounds__(512, 2) void k_fused(
    const float* __restrict__ x,
    const float* __restrict__ W1,  const float* __restrict__ b1,
    const float* __restrict__ g1,  const float* __restrict__ beta1,
    const float* __restrict__ We1, const float* __restrict__ be1,
    const float* __restrict__ ge1, const float* __restrict__ bte1,
    const float* __restrict__ We2, const float* __restrict__ be2,
    const float* __restrict__ ge2, const float* __restrict__ bte2,
    const float* __restrict__ Wg1, const float* __restrict__ bg1,
    const float* __restrict__ Wg2, const float* __restrict__ bg2,
    float* ws, float* __restrict__ out)
{
    cg::grid_group grid = cg::this_grid();
    __shared__ float Hs[NPB * 65];   // 64 nodes x 64 dims, stride 65 (2-way alias only)

    float* PMAX1 = ws;
    float* PMIN1 = ws + 8192;
    float* PMAX2 = ws + 16384;
    float* PMIN2 = ws + 24576;
    float* PSUM  = ws + 32768;
    float* PMXP  = ws + 40960;

    const int b  = blockIdx.x >> 2;
    const int g  = blockIdx.x & 3;
    const int l  = threadIdx.x & 63;                                 // node lane
    const int w  = __builtin_amdgcn_readfirstlane(threadIdx.x >> 6); // wave 0..7 (SGPR)
    const int n  = g * NPB + l;
    const int d0 = w * 8;                                            // wave's dim slice
    const int pidx = (b * GG + g) * DD + d0;

    // ================= Phase A: layer1 + conv1 matvec =================
    {
        float4 xv = *(const float4*)(x + ((size_t)b * NN + n) * 4);
        float a[8];
#pragma unroll
        for (int j = 0; j < 8; ++j) a[j] = b1[d0 + j];
#pragma unroll
        for (int j = 0; j < 8; ++j) a[j] = fmaf(xv.x, W1[0 * DD + d0 + j], a[j]);
#pragma unroll
        for (int j = 0; j < 8; ++j) a[j] = fmaf(xv.y, W1[1 * DD + d0 + j], a[j]);
#pragma unroll
        for (int j = 0; j < 8; ++j) a[j] = fmaf(xv.z, W1[2 * DD + d0 + j], a[j]);
#pragma unroll
        for (int j = 0; j < 8; ++j) a[j] = fmaf(xv.w, W1[3 * DD + d0 + j], a[j]);
#pragma unroll
        for (int j = 0; j < 8; ++j)
            Hs[l * 65 + d0 + j] = g1[d0 + j] * fmaxf(a[j], 0.f) + beta1[d0 + j];
    }
    __syncthreads();

    float ti[8], tj[8];
    matvec64(Hs + l * 65, d0, We1, ti, tj);          // ti stays in registers
    red_minmax_store(tj, l, PMAX1, PMIN1, pidx);

    grid.sync();

    // ============ Phase B: conv1 epilogue + conv2 matvec ============
    {
        float rmax[8], rmin[8];
#pragma unroll
        for (int j = 0; j < 8; ++j) {
            const int base = b * GG * DD + d0 + j;
            rmax[j] = fmaxf(fmaxf(PMAX1[base],          PMAX1[base + DD]),
                            fmaxf(PMAX1[base + 2 * DD], PMAX1[base + 3 * DD]));
            rmin[j] = fminf(fminf(PMIN1[base],          PMIN1[base + DD]),
                            fminf(PMIN1[base + 2 * DD], PMIN1[base + 3 * DD]));
        }
#pragma unroll
        for (int j = 0; j < 8; ++j) {
            float gv = ge1[d0 + j];
            float sv = ti[j] + (gv >= 0.f ? rmax[j] : rmin[j]) + be1[d0 + j];
            Hs[l * 65 + d0 + j] = gv * fmaxf(sv, 0.f) + bte1[d0 + j];
        }
    }
    __syncthreads();

    matvec64(Hs + l * 65, d0, We2, ti, tj);          // reuse ti/tj registers
    red_minmax_store(tj, l, PMAX2, PMIN2, pidx);

    grid.sync();

    // ============ Phase C: conv2 epilogue + pooling partials ============
    {
        float rmax[8], rmin[8];
#pragma unroll
        for (int j = 0; j < 8; ++j) {
            const int base = b * GG * DD + d0 + j;
            rmax[j] = fmaxf(fmaxf(PMAX2[base],          PMAX2[base + DD]),
                            fmaxf(PMAX2[base + 2 * DD], PMAX2[base + 3 * DD]));
            rmin[j] = fminf(fminf(PMIN2[base],          PMIN2[base + DD]),
                            fminf(PMIN2[base + 2 * DD], PMIN2[base + 3 * DD]));
        }
        float hv[8];
#pragma unroll
        for (int j = 0; j < 8; ++j) {
            float gv = ge2[d0 + j];
            float sv = ti[j] + (gv >= 0.f ? rmax[j] : rmin[j]) + be2[d0 + j];
            hv[j] = gv * fmaxf(sv, 0.f) + bte2[d0 + j];
        }
        // butterfly sum & max over the 64 nodes
        float sm[8], mx[8];
#pragma unroll
        for (int j = 0; j < 8; ++j) { sm[j] = hv[j]; mx[j] = hv[j]; }
#pragma unroll
        for (int m = 1; m < 64; m <<= 1) {
#pragma unroll
            for (int j = 0; j < 8; ++j) {
                sm[j] += __shfl_xor(sm[j], m, 64);
                mx[j] = fmaxf(mx[j], __shfl_xor(mx[j], m, 64));
            }
        }
        float ssm = sm[0], smx = mx[0];
#pragma unroll
        for (int j = 1; j < 8; ++j) {
            ssm = (l == j) ? sm[j] : ssm;
            smx = (l == j) ? mx[j] : smx;
        }
        if (l < 8) {
            PSUM[pidx + l] = ssm;
            PMXP[pidx + l] = smx;
        }
    }

    grid.sync();

    // ============ Phase D: pooling finalize + head MLP (g==0 blocks) ============
    if (g == 0) {
        const int t = threadIdx.x;
        float* xg  = Hs;         // [128], reuse LDS
        float* hid = Hs + 128;   // [64]
        if (t < 64) {
            float s = PSUM[(b * GG + 0) * DD + t] + PSUM[(b * GG + 1) * DD + t]
                    + PSUM[(b * GG + 2) * DD + t] + PSUM[(b * GG + 3) * DD + t];
            xg[t] = s * (1.f / 256.f);
        } else if (t < 128) {
            int d = t - 64;
            xg[64 + d] = fmaxf(fmaxf(PMXP[(b * GG + 0) * DD + d], PMXP[(b * GG + 1) * DD + d]),
                               fmaxf(PMXP[(b * GG + 2) * DD + d], PMXP[(b * GG + 3) * DD + d]));
        }
        __syncthreads();
        if (t < 64) {
            float a = bg1[t];
#pragma unroll
            for (int k = 0; k < 2 * DD; ++k) a = fmaf(xg[k], Wg1[k * DD + t], a);
            hid[t] = fmaxf(a, 0.f);
        }
        __syncthreads();
        if (t < 2) {
            float o = bg2[t];
#pragma unroll
            for (int j = 0; j < DD; ++j) o = fmaf(hid[j], Wg2[j * 2 + t], o);
            out[b * 2 + t] = o;
        }
    }
}

extern "C" void kernel_launch(void* const* d_in, const int* in_sizes, int n_in,
                              void* d_out, int out_size, void* d_ws, size_t ws_size,
                              hipStream_t stream) {
    const float* x     = (const float*)d_in[0];
    const float* W1    = (const float*)d_in[1];
    const float* b1    = (const float*)d_in[2];
    const float* g1    = (const float*)d_in[3];
    const float* beta1 = (const float*)d_in[4];
    const float* We1   = (const float*)d_in[5];
    const float* be1   = (const float*)d_in[6];
    const float* ge1   = (const float*)d_in[7];
    const float* bte1  = (const float*)d_in[8];
    const float* We2   = (const float*)d_in[9];
    const float* be2   = (const float*)d_in[10];
    const float* ge2   = (const float*)d_in[11];
    const float* bte2  = (const float*)d_in[12];
    const float* Wg1   = (const float*)d_in[13];
    const float* bg1   = (const float*)d_in[14];
    const float* Wg2   = (const float*)d_in[15];
    const float* bg2   = (const float*)d_in[16];
    float* ws   = (float*)d_ws;
    float* outp = (float*)d_out;

    void* args[] = { &x, &W1, &b1, &g1, &beta1,
                     &We1, &be1, &ge1, &bte1,
                     &We2, &be2, &ge2, &bte2,
                     &Wg1, &bg1, &Wg2, &bg2,
                     &ws, &outp };

    hipLaunchCooperativeKernel((const void*)k_fused, dim3(NB * GG), dim3(512),
                               args, 0, stream);
}

// Round 2
// 151.648 us; speedup vs baseline: 1.3445x; 1.3445x over previous
//
#include <hip/hip_runtime.h>

#define NB 32
#define NN 256
#define DD 64
#define GG 4            // node-groups per batch
#define NPB 64          // nodes per block
#define FMAXV 3.402823466e+38f

// R8: 2-dispatch pipeline (R6 had 4; R7's cooperative fusion FAILED -- each
// grid.sync costs ~25-30us of cross-XCD L2 writeback/invalidate, kernel went
// to ~90us). Timed window model: ~113us is harness 256MiB re-poison fills
// (fixed floor, calibrated from R7: 203.9 total - 91 kernel); our controllable
// share was ~8us across 4 dispatches. This version keeps the two heavy
// matvec stages as separate dispatches (full per-batch barriers) and absorbs
// the cheap conv2-epilogue + pooling + head into k2 via a last-block-per-batch
// atomic tail: publish partials -> __threadfence -> atomicAdd(CNT[b]); the
// 4th arriver acquires and finishes the batch (~1.5us, 32 vals/thread).
// CNT is zeroed by k1 every iteration (poison-proof, stream-ordered).
//
// ws layout (floats):
//   TI    @ 0        NB*NN*DD = 524288
//   PMAX1 @ 524288   NB*GG*DD = 8192
//   PMIN1 @ 532480   8192
//   PMAX2 @ 540672   8192
//   PMIN2 @ 548864   8192
//   CNT   @ 557056   32 (int)

__global__ __launch_bounds__(512) void k_conv1(
    const float* __restrict__ x,
    const float* __restrict__ W1,  const float* __restrict__ b1,
    const float* __restrict__ g1,  const float* __restrict__ beta1,
    const float* __restrict__ We1,
    float* __restrict__ TI, float* __restrict__ PMAX, float* __restrict__ PMIN,
    int* __restrict__ CNT)
{
    __shared__ float Hs[NPB * 65];   // 64 nodes x 64 dims, stride 65 (2-way alias only)
    const int b  = blockIdx.x >> 2;
    const int g  = blockIdx.x & 3;
    const int l  = threadIdx.x & 63;                                // node lane
    const int w  = __builtin_amdgcn_readfirstlane(threadIdx.x >> 6); // wave 0..7 (SGPR)
    const int n  = g * NPB + l;
    const int d0 = w * 8;                                           // wave's dim slice

    // zero the per-batch tail counters for this iteration (poison-proof)
    if (g == 0 && threadIdx.x == 0) CNT[b] = 0;

    // ---- layer 1: h[n, d0..d0+8] = bn(relu(x @ W1 + b1)) ----
    {
        float4 xv = *(const float4*)(x + ((size_t)b * NN + n) * 4);
        float a[8];
#pragma unroll
        for (int j = 0; j < 8; ++j) a[j] = b1[d0 + j];
#pragma unroll
        for (int j = 0; j < 8; ++j) a[j] = fmaf(xv.x, W1[0 * DD + d0 + j], a[j]);
#pragma unroll
        for (int j = 0; j < 8; ++j) a[j] = fmaf(xv.y, W1[1 * DD + d0 + j], a[j]);
#pragma unroll
        for (int j = 0; j < 8; ++j) a[j] = fmaf(xv.z, W1[2 * DD + d0 + j], a[j]);
#pragma unroll
        for (int j = 0; j < 8; ++j) a[j] = fmaf(xv.w, W1[3 * DD + d0 + j], a[j]);
#pragma unroll
        for (int j = 0; j < 8; ++j)
            Hs[l * 65 + d0 + j] = g1[d0 + j] * fmaxf(a[j], 0.f) + beta1[d0 + j];
    }
    __syncthreads();

    // ---- conv1 matvec: ti/tj[d0..d0+8] for node n; weights via s_load ----
    float ti[8], tj[8];
#pragma unroll
    for (int j = 0; j < 8; ++j) { ti[j] = 0.f; tj[j] = 0.f; }
#pragma unroll
    for (int k = 0; k < DD; ++k) {
        const float hk = Hs[l * 65 + k];
        const float* wi = We1 + k * DD + d0;          // wave-uniform address
        const float* wj = We1 + (DD + k) * DD + d0;   // wave-uniform address
#pragma unroll
        for (int j = 0; j < 8; ++j) {
            ti[j] = fmaf(hk, wi[j], ti[j]);
            tj[j] = fmaf(hk, wj[j], tj[j]);
        }
    }
    // store ti -> ws
    {
        float* o = TI + ((size_t)(b * NN + n)) * DD + d0;
        *(float4*)(o)     = make_float4(ti[0], ti[1], ti[2], ti[3]);
        *(float4*)(o + 4) = make_float4(ti[4], ti[5], ti[6], ti[7]);
    }
    // butterfly max/min of tj over the 64 nodes (lanes)
    float mx[8], mn[8];
#pragma unroll
    for (int j = 0; j < 8; ++j) { mx[j] = tj[j]; mn[j] = tj[j]; }
#pragma unroll
    for (int m = 1; m < 64; m <<= 1) {
#pragma unroll
        for (int j = 0; j < 8; ++j) {
            mx[j] = fmaxf(mx[j], __shfl_xor(mx[j], m, 64));
            mn[j] = fminf(mn[j], __shfl_xor(mn[j], m, 64));
        }
    }
    float smx = mx[0], smn = mn[0];
#pragma unroll
    for (int j = 1; j < 8; ++j) {
        smx = (l == j) ? mx[j] : smx;
        smn = (l == j) ? mn[j] : smn;
    }
    if (l < 8) {
        PMAX[(b * GG + g) * DD + d0 + l] = smx;
        PMIN[(b * GG + g) * DD + d0 + l] = smn;
    }
}

// conv1 epilogue + conv2 matvec + (last block per batch) pooling + head MLP
__global__ __launch_bounds__(512) void k_conv2_tail(
    const float* PMAXin, const float* PMINin,
    const float* __restrict__ be1P, const float* __restrict__ ge1P,
    const float* __restrict__ bte1P,
    const float* __restrict__ We,
    const float* __restrict__ be2P, const float* __restrict__ ge2P,
    const float* __restrict__ bte2P,
    const float* __restrict__ Wg1, const float* __restrict__ bg1,
    const float* __restrict__ Wg2, const float* __restrict__ bg2,
    float* TI, float* PMAX, float* PMIN, int* CNT,
    float* __restrict__ out)
{
    __shared__ float Hs[NPB * 65];
    __shared__ int amLast;
    const int b  = blockIdx.x >> 2;
    const int g  = blockIdx.x & 3;
    const int l  = threadIdx.x & 63;
    const int w  = __builtin_amdgcn_readfirstlane(threadIdx.x >> 6);
    const int n  = g * NPB + l;
    const int d0 = w * 8;

    // combine the 4 per-group conv1 partials
    float rmax[8], rmin[8];
#pragma unroll
    for (int j = 0; j < 8; ++j) {
        const int base = b * GG * DD + d0 + j;
        rmax[j] = fmaxf(fmaxf(PMAXin[base],          PMAXin[base + DD]),
                        fmaxf(PMAXin[base + 2 * DD], PMAXin[base + 3 * DD]));
        rmin[j] = fminf(fminf(PMINin[base],          PMINin[base + DD]),
                        fminf(PMINin[base + 2 * DD], PMINin[base + 3 * DD]));
    }
    // conv1 epilogue: h = ge1*relu(ti_prev + pick + be1) + bte1  (monotone bn o max)
    {
        const float* tip = TI + ((size_t)(b * NN + n)) * DD + d0;
        float4 t0 = *(const float4*)tip;
        float4 t1 = *(const float4*)(tip + 4);
        float tiv[8] = {t0.x, t0.y, t0.z, t0.w, t1.x, t1.y, t1.z, t1.w};
#pragma unroll
        for (int j = 0; j < 8; ++j) {
            float gv = ge1P[d0 + j];
            float sv = tiv[j] + (gv >= 0.f ? rmax[j] : rmin[j]) + be1P[d0 + j];
            Hs[l * 65 + d0 + j] = gv * fmaxf(sv, 0.f) + bte1P[d0 + j];
        }
    }
    __syncthreads();

    // conv2 matvec
    float ti[8], tj[8];
#pragma unroll
    for (int j = 0; j < 8; ++j) { ti[j] = 0.f; tj[j] = 0.f; }
#pragma unroll
    for (int k = 0; k < DD; ++k) {
        const float hk = Hs[l * 65 + k];
        const float* wi = We + k * DD + d0;
        const float* wj = We + (DD + k) * DD + d0;
#pragma unroll
        for (int j = 0; j < 8; ++j) {
            ti[j] = fmaf(hk, wi[j], ti[j]);
            tj[j] = fmaf(hk, wj[j], tj[j]);
        }
    }
    {
        float* o = TI + ((size_t)(b * NN + n)) * DD + d0;   // in-place: same thread read it
        *(float4*)(o)     = make_float4(ti[0], ti[1], ti[2], ti[3]);
        *(float4*)(o + 4) = make_float4(ti[4], ti[5], ti[6], ti[7]);
    }
    float mx[8], mn[8];
#pragma unroll
    for (int j = 0; j < 8; ++j) { mx[j] = tj[j]; mn[j] = tj[j]; }
#pragma unroll
    for (int m = 1; m < 64; m <<= 1) {
#pragma unroll
        for (int j = 0; j < 8; ++j) {
            mx[j] = fmaxf(mx[j], __shfl_xor(mx[j], m, 64));
            mn[j] = fminf(mn[j], __shfl_xor(mn[j], m, 64));
        }
    }
    float smx = mx[0], smn = mn[0];
#pragma unroll
    for (int j = 1; j < 8; ++j) {
        smx = (l == j) ? mx[j] : smx;
        smn = (l == j) ? mn[j] : smn;
    }
    if (l < 8) {
        PMAX[(b * GG + g) * DD + d0 + l] = smx;
        PMIN[(b * GG + g) * DD + d0 + l] = smn;
    }

    // ---- publish, then last-arriving block of this batch finishes it ----
    __threadfence();                 // release: all waves' stores -> device scope
    __syncthreads();                 // all waves of this block have fenced
    if (threadIdx.x == 0) {
        int old = atomicAdd(&CNT[b], 1);   // device-scope by default
        amLast = (old == GG - 1);
    }
    __syncthreads();
    if (!amLast) return;

    __threadfence();                 // acquire: invalidate stale cached lines

    // combine the 4 per-group conv2 partials
    float rmax2[8], rmin2[8];
#pragma unroll
    for (int j = 0; j < 8; ++j) {
        const int base = b * GG * DD + d0 + j;
        rmax2[j] = fmaxf(fmaxf(PMAX[base],          PMAX[base + DD]),
                         fmaxf(PMAX[base + 2 * DD], PMAX[base + 3 * DD]));
        rmin2[j] = fminf(fminf(PMIN[base],          PMIN[base + DD]),
                         fminf(PMIN[base + 2 * DD], PMIN[base + 3 * DD]));
    }
    // conv2 epilogue + pooled sum/max over all 256 nodes (4 per lane)
    float sm[8], mxp[8];
#pragma unroll
    for (int j = 0; j < 8; ++j) { sm[j] = 0.f; mxp[j] = -FMAXV; }
#pragma unroll
    for (int c = 0; c < 4; ++c) {
        const int n2 = c * 64 + l;
        const float* tip = TI + ((size_t)(b * NN + n2)) * DD + d0;
        float4 t0 = *(const float4*)tip;
        float4 t1 = *(const float4*)(tip + 4);
        float tiv[8] = {t0.x, t0.y, t0.z, t0.w, t1.x, t1.y, t1.z, t1.w};
#pragma unroll
        for (int j = 0; j < 8; ++j) {
            float gv = ge2P[d0 + j];
            float sv = tiv[j] + (gv >= 0.f ? rmax2[j] : rmin2[j]) + be2P[d0 + j];
            float hv = gv * fmaxf(sv, 0.f) + bte2P[d0 + j];
            sm[j] += hv;
            mxp[j] = fmaxf(mxp[j], hv);
        }
    }
#pragma unroll
    for (int m = 1; m < 64; m <<= 1) {
#pragma unroll
        for (int j = 0; j < 8; ++j) {
            sm[j] += __shfl_xor(sm[j], m, 64);
            mxp[j] = fmaxf(mxp[j], __shfl_xor(mxp[j], m, 64));
        }
    }
    float ssm = sm[0], smxp = mxp[0];
#pragma unroll
    for (int j = 1; j < 8; ++j) {
        ssm  = (l == j) ? sm[j]  : ssm;
        smxp = (l == j) ? mxp[j] : smxp;
    }
    float* xg  = Hs;         // [128] mean | max, reuse LDS (post-barrier)
    float* hid = Hs + 128;   // [64]
    __syncthreads();         // Hs reuse: conv-stage reads are long done
    if (l < 8) {
        xg[d0 + l]      = ssm * (1.f / 256.f);
        xg[64 + d0 + l] = smxp;
    }
    __syncthreads();
    // head MLP
    const int t = threadIdx.x;
    if (t < 64) {
        float a = bg1[t];
#pragma unroll
        for (int k = 0; k < 2 * DD; ++k) a = fmaf(xg[k], Wg1[k * DD + t], a);
        hid[t] = fmaxf(a, 0.f);
    }
    __syncthreads();
    if (t < 2) {
        float o = bg2[t];
#pragma unroll
        for (int j = 0; j < DD; ++j) o = fmaf(hid[j], Wg2[j * 2 + t], o);
        out[b * 2 + t] = o;
    }
}

extern "C" void kernel_launch(void* const* d_in, const int* in_sizes, int n_in,
                              void* d_out, int out_size, void* d_ws, size_t ws_size,
                              hipStream_t stream) {
    const float* x     = (const float*)d_in[0];
    const float* W1    = (const float*)d_in[1];
    const float* b1    = (const float*)d_in[2];
    const float* g1    = (const float*)d_in[3];
    const float* beta1 = (const float*)d_in[4];
    const float* We1   = (const float*)d_in[5];
    const float* be1   = (const float*)d_in[6];
    const float* ge1   = (const float*)d_in[7];
    const float* bte1  = (const float*)d_in[8];
    const float* We2   = (const float*)d_in[9];
    const float* be2   = (const float*)d_in[10];
    const float* ge2   = (const float*)d_in[11];
    const float* bte2  = (const float*)d_in[12];
    const float* Wg1   = (const float*)d_in[13];
    const float* bg1   = (const float*)d_in[14];
    const float* Wg2   = (const float*)d_in[15];
    const float* bg2   = (const float*)d_in[16];

    float* ws    = (float*)d_ws;
    float* TI    = ws;
    float* PMAX1 = ws + 524288;
    float* PMIN1 = ws + 532480;
    float* PMAX2 = ws + 540672;
    float* PMIN2 = ws + 548864;
    int*   CNT   = (int*)(ws + 557056);

    k_conv1<<<dim3(NB * GG), dim3(512), 0, stream>>>(
        x, W1, b1, g1, beta1, We1, TI, PMAX1, PMIN1, CNT);
    k_conv2_tail<<<dim3(NB * GG), dim3(512), 0, stream>>>(
        PMAX1, PMIN1, be1, ge1, bte1, We2, be2, ge2, bte2,
        Wg1, bg1, Wg2, bg2, TI, PMAX2, PMIN2, CNT, (float*)d_out);
}